// Round 8
// baseline (588.834 us; speedup 1.0000x reference)
//
#include <hip/hip_runtime.h>
#include <cstdint>

// ---------------------------------------------------------------------------
// ConvModule: LN -> GEMM(512->1024)+SiLU -> conv K=5 (1024->1024) -> GLU ->
//             BN -> GEMM(512->512).  B=16, T=1024, C=512. fp32 I/O, bf16 MFMA.
// Round 8: all-LDS operands (TCP path is 64B/cyc, LDS is 128B/cyc and runs in
// parallel).  Full A+B double-buffer (123.5KB, 1 block/CU), ONE barrier per
// chunk, register-relay staging ordered write(j+1) -> load(j+2) -> MFMA(j)
// so loads get a full chunk of latency cover before the barrier drain.
// Stride-40 rows everywhere (2-way conflicts = free). R4 coalesced epilogue.
// Lessons: direct-global frag loads = 16 lines each -> TCP-bound ~330us
// (R4/R6/R7); unpadded LDS B = 8-way conflicts (R3); >2-deep array prefetch
// spills (R5); grid x must be m-tile or A is fetched per-XCD (R7).
// ---------------------------------------------------------------------------

#define NB    16
#define TT    1024
#define CC    512
#define C2    1024
#define TPAD  1028        // T + 4 pad rows (2 each side) per batch

typedef unsigned short u16;
typedef short bf16x8 __attribute__((ext_vector_type(8)));
typedef float f32x4  __attribute__((ext_vector_type(4)));

__device__ __forceinline__ float bf2f(u16 u) {
  union { unsigned int i; float f; } v; v.i = ((unsigned int)u) << 16; return v.f;
}
__device__ __forceinline__ u16 f2bf(float f) {
  union { float f; unsigned int i; } v; v.f = f;
  unsigned int x = v.i;
  return (u16)((x + 0x7fffu + ((x >> 16) & 1u)) >> 16);  // RNE
}

// ---------------------------------------------------------------------------
__global__ __launch_bounds__(256) void prep_k(
    const float* __restrict__ w1, u16* __restrict__ w1b,
    const float* __restrict__ w3, u16* __restrict__ w3b,
    u16* __restrict__ h1p) {
  const int b = blockIdx.x;
  if (b < 512) {
    const int i = (b * 256 + threadIdx.x) * 4;
    float4 v = *(const float4*)(w1 + i);
    u16 o[4] = { f2bf(v.x), f2bf(v.y), f2bf(v.z), f2bf(v.w) };
    *(uint2*)(w1b + i) = *(const uint2*)o;
  } else if (b < 768) {
    const int i = ((b - 512) * 256 + threadIdx.x) * 4;
    float4 v = *(const float4*)(w3 + i);
    u16 o[4] = { f2bf(v.x), f2bf(v.y), f2bf(v.z), f2bf(v.w) };
    *(uint2*)(w3b + i) = *(const uint2*)o;
  } else {
    const int idx = (b - 768) * 256 + threadIdx.x;
    const int bb  = idx >> 9;
    const int rem = idx & 511;
    const int ri  = rem >> 7;
    const int c8  = (rem & 127) * 8;
    const int row = bb * TPAD + (ri < 2 ? ri : 1024 + ri);   // 0,1,1026,1027
    uint4 z = make_uint4(0u, 0u, 0u, 0u);
    *(uint4*)(h1p + (size_t)row * C2 + c8) = z;
  }
}

// ---------------------------------------------------------------------------
// w2 fp32 (K, I, O) -> w2t bf16 (K, O, I)
__global__ void transpose_w2(const float* __restrict__ w2, u16* __restrict__ w2t) {
  __shared__ u16 t[64][65];
  const int k  = blockIdx.z;
  const int i0 = blockIdx.x * 64, o0 = blockIdx.y * 64;
  const int tx = threadIdx.x, ty = threadIdx.y;
  for (int r = ty; r < 64; r += 4)
    t[r][tx] = f2bf(w2[((size_t)(k * C2) + i0 + r) * C2 + o0 + tx]);
  __syncthreads();
  for (int r = ty; r < 64; r += 4)
    w2t[((size_t)(k * C2) + o0 + r) * C2 + i0 + tx] = t[tx][r];
}

// ---------------------------------------------------------------------------
__global__ __launch_bounds__(256) void layernorm_k(
    const float* __restrict__ x, const float* __restrict__ lng,
    const float* __restrict__ lnb, u16* __restrict__ out) {
  const int tok  = blockIdx.x * 4 + (threadIdx.x >> 6);
  const int lane = threadIdx.x & 63;
  const float* xp = x + (size_t)tok * CC + lane * 8;
  float f[8];
  *(float4*)(f)     = *(const float4*)(xp);
  *(float4*)(f + 4) = *(const float4*)(xp + 4);
  float s = 0.f, s2 = 0.f;
#pragma unroll
  for (int j = 0; j < 8; j++) { s += f[j]; s2 += f[j] * f[j]; }
#pragma unroll
  for (int m = 32; m >= 1; m >>= 1) { s += __shfl_xor(s, m, 64); s2 += __shfl_xor(s2, m, 64); }
  const float mu  = s  * (1.f / 512.f);
  const float var = s2 * (1.f / 512.f) - mu * mu;
  const float rs  = rsqrtf(var + 1e-5f);
  u16 ov[8];
#pragma unroll
  for (int j = 0; j < 8; j++) {
    const int c = lane * 8 + j;
    ov[j] = f2bf((f[j] - mu) * rs * lng[c] + lnb[c]);
  }
  *(uint4*)(out + (size_t)tok * CC + lane * 8) = *(const uint4*)ov;
}

// ---------------------------------------------------------------------------
// GEMM out[m,n] = sum_k A[m,k]*Bt[n,k] + bias[n].  128x128 tile, BK=32.
// A and B both LDS double-buffered (stride 40), register-relay staging,
// 1 barrier per chunk.  3 blocks/CU.
// EPI 0: SiLU, bf16 -> h1p padded rows.  EPI 1: fp32 -> out (ld CC).
template <int EPI>
__global__ __launch_bounds__(256, 3) void gemm_bt(
    const u16* __restrict__ A, const u16* __restrict__ Bt,
    const float* __restrict__ bias, void* __restrict__ outv,
    const int Kd, const int ldA) {
  __shared__ __align__(16) u16 smem[20480];   // lsA 2x5120 | lsB 2x5120
  const int tid  = threadIdx.x;
  const int m0   = blockIdx.x * 128;          // x = m-tile (A fetched once)
  const int n0   = blockIdx.y * 128;
  const int wave = tid >> 6, lane = tid & 63;
  const int wm = (wave & 1) * 64, wn = (wave >> 1) * 64;
  const int quad = lane >> 4, l16 = lane & 15;
  const int row = tid >> 2;            // 0..63
  const int kc  = (tid & 3) * 8;       // 0/8/16/24
  const int J = Kd >> 5;               // 16

  const u16* Ap0 = A + (size_t)(m0 + row) * ldA + kc;
  const u16* Ap1 = Ap0 + (size_t)64 * ldA;
  const u16* Bp0 = Bt + (size_t)(n0 + row) * Kd + kc;
  const u16* Bp1 = Bp0 + (size_t)64 * Kd;

  f32x4 acc[4][4] = {};
  // prologue: chunk0 -> buf0; chunk1 -> regs
  uint4 rA0 = *(const uint4*)Ap0, rA1 = *(const uint4*)Ap1;
  uint4 rB0 = *(const uint4*)Bp0, rB1 = *(const uint4*)Bp1;
  *(uint4*)(smem + row * 40 + kc)                = rA0;
  *(uint4*)(smem + (64 + row) * 40 + kc)         = rA1;
  *(uint4*)(smem + 10240 + row * 40 + kc)        = rB0;
  *(uint4*)(smem + 10240 + (64 + row) * 40 + kc) = rB1;
  rA0 = *(const uint4*)(Ap0 + 32); rA1 = *(const uint4*)(Ap1 + 32);
  rB0 = *(const uint4*)(Bp0 + 32); rB1 = *(const uint4*)(Bp1 + 32);
  __syncthreads();

#pragma unroll 1
  for (int j = 0; j < J; j++) {
    const u16* curA = smem + (j & 1) * 5120;
    const u16* curB = smem + 10240 + (j & 1) * 5120;
    // 1) write chunk j+1 from relay regs (loads are >=1 chunk old)
    if (j + 1 < J) {
      u16* nxtA = smem + ((j + 1) & 1) * 5120;
      u16* nxtB = smem + 10240 + ((j + 1) & 1) * 5120;
      *(uint4*)(nxtA + row * 40 + kc)        = rA0;
      *(uint4*)(nxtA + (64 + row) * 40 + kc) = rA1;
      *(uint4*)(nxtB + row * 40 + kc)        = rB0;
      *(uint4*)(nxtB + (64 + row) * 40 + kc) = rB1;
    }
    // 2) issue relay loads for chunk j+2 (drained at end-of-chunk barrier)
    {
      const int k2 = (j + 2 < J) ? (j + 2) * 32 : 0;
      rA0 = *(const uint4*)(Ap0 + k2); rA1 = *(const uint4*)(Ap1 + k2);
      rB0 = *(const uint4*)(Bp0 + k2); rB1 = *(const uint4*)(Bp1 + k2);
    }
    // 3) compute chunk j
    bf16x8 af[4], bfr[4];
#pragma unroll
    for (int i = 0; i < 4; i++)
      af[i] = *(const bf16x8*)(curA + (wm + i * 16 + l16) * 40 + quad * 8);
#pragma unroll
    for (int i = 0; i < 4; i++)
      bfr[i] = *(const bf16x8*)(curB + (wn + i * 16 + l16) * 40 + quad * 8);
#pragma unroll
    for (int mi = 0; mi < 4; mi++)
#pragma unroll
      for (int ni = 0; ni < 4; ni++)
        acc[mi][ni] = __builtin_amdgcn_mfma_f32_16x16x32_bf16(
            af[mi], bfr[ni], acc[mi][ni], 0, 0, 0);
    __syncthreads();
  }

  float bv[4];
#pragma unroll
  for (int ni = 0; ni < 4; ni++) bv[ni] = bias[n0 + wn + ni * 16 + l16];

  if (EPI == 0) {
    u16* epi = smem + wave * 4608;       // 64 x 72 u16, private
#pragma unroll
    for (int mi = 0; mi < 4; mi++)
#pragma unroll
      for (int ni = 0; ni < 4; ni++)
#pragma unroll
        for (int r = 0; r < 4; r++) {
          float v = acc[mi][ni][r] + bv[ni];
          v = v / (1.f + __expf(-v));    // SiLU
          epi[(mi * 16 + quad * 4 + r) * 72 + ni * 16 + l16] = f2bf(v);
        }
    u16* h1p = (u16*)outv;
#pragma unroll
    for (int p = 0; p < 8; p++) {
      const int rrow = p * 8 + (lane >> 3);
      const int colb = (lane & 7) * 8;
      uint4 v = *(const uint4*)(epi + rrow * 72 + colb);
      const int rr = m0 + wm + rrow;
      const int bb = rr >> 10, tt = rr & 1023;
      *(uint4*)(h1p + (size_t)(bb * TPAD + tt + 2) * C2 + n0 + wn + colb) = v;
    }
  } else {
    float* fepi = (float*)(smem + wave * 4608);   // 2 x (16 x 68) f32
    float* outf = (float*)outv;
#pragma unroll
    for (int mi = 0; mi < 4; mi++) {
      float* fp = fepi + (mi & 1) * 1088;
#pragma unroll
      for (int ni = 0; ni < 4; ni++)
#pragma unroll
        for (int r = 0; r < 4; r++)
          fp[(quad * 4 + r) * 68 + ni * 16 + l16] = acc[mi][ni][r] + bv[ni];
#pragma unroll
      for (int p = 0; p < 4; p++) {
        const int rrow = p * 4 + (lane >> 4);
        const int col  = (lane & 15) * 4;
        float4 v = *(const float4*)(fp + rrow * 68 + col);
        *(float4*)(outf + (size_t)(m0 + wm + mi * 16 + rrow) * CC + n0 + wn + col) = v;
      }
    }
  }
}

// ---------------------------------------------------------------------------
// 5-tap conv: A (132x32) and B (5x128x32) both LDS double-buffered, stride-40
// rows, register-relay staging (A: 2-3 uint4/thread, B: 10 uint4/thread),
// ONE barrier per chunk.  LDS 123.5 KB -> 1 block/CU.
__global__ __launch_bounds__(256, 1) void conv5_mfma(
    const u16* __restrict__ h1p, const u16* __restrict__ w2t,
    const float* __restrict__ b2, u16* __restrict__ out) {
  __shared__ __align__(16) u16 smem[61760];  // lsA 2x5280 | lsB 2x25600 @10560
  const int tid = threadIdx.x;
  const int mt  = blockIdx.x;                // x = m-tile
  const int n0  = blockIdx.y * 128;
  const int bb  = mt >> 3;
  const int t0  = (mt & 7) * 128;
  const size_t arow0 = (size_t)bb * TPAD + t0;
  const int wave = tid >> 6, lane = tid & 63;
  const int wm = (wave & 1) * 64, wn = (wave >> 1) * 64;
  const int quad = lane >> 4, l16 = lane & 15;
  const int row = tid >> 2;
  const int kc  = (tid & 3) * 8;

  const u16* Ap0 = h1p + (arow0 + row) * C2 + kc;
  const u16* Ap1 = Ap0 + (size_t)64 * C2;
  const u16* Ap2 = h1p + (arow0 + 128 + row) * C2 + kc;   // tid<16

  f32x4 acc[4][4] = {};
  uint4 rA0, rA1, rA2, rB[10];

  // prologue: chunk0 -> buf0
  rA0 = *(const uint4*)Ap0; rA1 = *(const uint4*)Ap1;
  if (tid < 16) rA2 = *(const uint4*)Ap2;
#pragma unroll
  for (int q = 0; q < 10; q++) {
    const int f = q * 256 + tid;
    const int tap = f >> 9, rr = (f >> 2) & 127, cc = (f & 3) * 8;
    rB[q] = *(const uint4*)(w2t + (size_t)(tap * C2 + n0 + rr) * C2 + cc);
  }
  *(uint4*)(smem + row * 40 + kc)        = rA0;
  *(uint4*)(smem + (64 + row) * 40 + kc) = rA1;
  if (tid < 16) *(uint4*)(smem + (128 + row) * 40 + kc) = rA2;
#pragma unroll
  for (int q = 0; q < 10; q++) {
    const int f = q * 256 + tid;
    const int tap = f >> 9, rr = (f >> 2) & 127, cc = (f & 3) * 8;
    *(uint4*)(smem + 10560 + tap * 5120 + rr * 40 + cc) = rB[q];
  }
  // chunk1 -> regs
  rA0 = *(const uint4*)(Ap0 + 32); rA1 = *(const uint4*)(Ap1 + 32);
  if (tid < 16) rA2 = *(const uint4*)(Ap2 + 32);
#pragma unroll
  for (int q = 0; q < 10; q++) {
    const int f = q * 256 + tid;
    const int tap = f >> 9, rr = (f >> 2) & 127, cc = (f & 3) * 8;
    rB[q] = *(const uint4*)(w2t + (size_t)(tap * C2 + n0 + rr) * C2 + 32 + cc);
  }
  __syncthreads();

#pragma unroll 1
  for (int j = 0; j < 32; j++) {
    const u16* curA = smem + (j & 1) * 5280;
    const u16* curB = smem + 10560 + (j & 1) * 25600;
    // 1) write chunk j+1 from relay regs
    if (j + 1 < 32) {
      u16* nxtA = smem + ((j + 1) & 1) * 5280;
      u16* nxtB = smem + 10560 + ((j + 1) & 1) * 25600;
      *(uint4*)(nxtA + row * 40 + kc)        = rA0;
      *(uint4*)(nxtA + (64 + row) * 40 + kc) = rA1;
      if (tid < 16) *(uint4*)(nxtA + (128 + row) * 40 + kc) = rA2;
#pragma unroll
      for (int q = 0; q < 10; q++) {
        const int f = q * 256 + tid;
        const int tap = f >> 9, rr = (f >> 2) & 127, cc = (f & 3) * 8;
        *(uint4*)(nxtB + tap * 5120 + rr * 40 + cc) = rB[q];
      }
    }
    // 2) relay loads for chunk j+2 (full chunk of latency cover)
    {
      const int i2 = (j + 2 < 32) ? (j + 2) * 32 : 0;
      rA0 = *(const uint4*)(Ap0 + i2);
      rA1 = *(const uint4*)(Ap1 + i2);
      if (tid < 16) rA2 = *(const uint4*)(Ap2 + i2);
#pragma unroll
      for (int q = 0; q < 10; q++) {
        const int f = q * 256 + tid;
        const int tap = f >> 9, rr = (f >> 2) & 127, cc = (f & 3) * 8;
        rB[q] = *(const uint4*)(w2t + (size_t)(tap * C2 + n0 + rr) * C2 + i2 + cc);
      }
    }
    // 3) compute chunk j: 5 taps x 16 MFMA
#pragma unroll
    for (int k = 0; k < 5; k++) {
      bf16x8 af[4], bfr[4];
#pragma unroll
      for (int i = 0; i < 4; i++)
        af[i] = *(const bf16x8*)(curA + (wm + i * 16 + l16 + k) * 40 + quad * 8);
#pragma unroll
      for (int i = 0; i < 4; i++)
        bfr[i] = *(const bf16x8*)(curB + k * 5120 + (wn + i * 16 + l16) * 40 + quad * 8);
#pragma unroll
      for (int mi = 0; mi < 4; mi++)
#pragma unroll
        for (int ni = 0; ni < 4; ni++)
          acc[mi][ni] = __builtin_amdgcn_mfma_f32_16x16x32_bf16(
              af[mi], bfr[ni], acc[mi][ni], 0, 0, 0);
    }
    __syncthreads();
  }

  float bv[4];
#pragma unroll
  for (int ni = 0; ni < 4; ni++) bv[ni] = b2[n0 + wn + ni * 16 + l16];

  u16* epi = smem + wave * 4608;         // 64 x 72 u16, private
#pragma unroll
  for (int mi = 0; mi < 4; mi++)
#pragma unroll
    for (int ni = 0; ni < 4; ni++)
#pragma unroll
      for (int r = 0; r < 4; r++)
        epi[(mi * 16 + quad * 4 + r) * 72 + ni * 16 + l16] = f2bf(acc[mi][ni][r] + bv[ni]);

  const size_t orow0 = (size_t)bb * TT + t0;
#pragma unroll
  for (int p = 0; p < 8; p++) {
    const int rrow = p * 8 + (lane >> 3);
    const int colb = (lane & 7) * 8;
    uint4 v = *(const uint4*)(epi + rrow * 72 + colb);
    *(uint4*)(out + (orow0 + wm + rrow) * C2 + n0 + wn + colb) = v;
  }
}

// ---------------------------------------------------------------------------
__global__ __launch_bounds__(256) void glu_bn_k(
    const u16* __restrict__ hc, const float* __restrict__ bg,
    const float* __restrict__ bb_, const float* __restrict__ bm,
    const float* __restrict__ bv, u16* __restrict__ out) {
  const int idx = blockIdx.x * 256 + threadIdx.x;
  const int r  = idx >> 6;
  const int c8 = (idx & 63) * 8;
  const u16* pa = hc + (size_t)r * C2 + c8;
  uint4 ra = *(const uint4*)pa;
  uint4 rg = *(const uint4*)(pa + CC);
  u16 av[8], gv[8], ov[8];
  *(uint4*)av = ra; *(uint4*)gv = rg;
#pragma unroll
  for (int j = 0; j < 8; j++) {
    const int c = c8 + j;
    const float a = bf2f(av[j]);
    const float g = bf2f(gv[j]);
    const float h = a / (1.f + __expf(-g));
    const float sc = bg[c] * rsqrtf(bv[c] + 1e-5f);
    ov[j] = f2bf((h - bm[c]) * sc + bb_[c]);
  }
  *(uint4*)(out + (size_t)r * CC + c8) = *(const uint4*)ov;
}

// ---------------------------------------------------------------------------
extern "C" void kernel_launch(void* const* d_in, const int* in_sizes, int n_in,
                              void* d_out, int out_size, void* d_ws, size_t ws_size,
                              hipStream_t stream) {
  const float* x   = (const float*)d_in[0];
  const float* lng = (const float*)d_in[1];
  const float* lnb = (const float*)d_in[2];
  const float* w1  = (const float*)d_in[3];
  const float* b1  = (const float*)d_in[4];
  const float* w2  = (const float*)d_in[5];
  const float* b2  = (const float*)d_in[6];
  const float* bng = (const float*)d_in[7];
  const float* bnb = (const float*)d_in[8];
  const float* bnm = (const float*)d_in[9];
  const float* bnv = (const float*)d_in[10];
  const float* w3  = (const float*)d_in[11];
  const float* b3  = (const float*)d_in[12];

  u16* ws  = (u16*)d_ws;
  u16* hln = ws;                               // 16384*512
  u16* h2  = hln;                              // alias (hln dead after GEMM1)
  u16* h1p = ws + 8388608;                     // 16*1028*1024
  u16* w2t = h1p + 16842752;                   // 5*1024*1024
  u16* hcv = w2t + 5242880;                    // 16384*1024
  u16* w1b = hcv + 16777216;                   // 1024*512
  u16* w3b = w1b + 524288;                     // 512*512

  prep_k      <<<800, 256, 0, stream>>>(w1, w1b, w3, w3b, h1p);
  transpose_w2<<<dim3(16, 16, 5), dim3(64, 4), 0, stream>>>(w2, w2t);
  layernorm_k <<<4096, 256, 0, stream>>>(x, lng, lnb, hln);
  gemm_bt<0>  <<<dim3(128, 8), 256, 0, stream>>>(hln, w1b, b1, h1p, 512, 512);
  conv5_mfma  <<<dim3(128, 8), 256, 0, stream>>>(h1p, w2t, b2, hcv);
  glu_bn_k    <<<4096, 256, 0, stream>>>(hcv, bng, bnb, bnm, bnv, h2);
  gemm_bt<1>  <<<dim3(128, 4), 256, 0, stream>>>(h2, w3b, b3, d_out, 512, 512);
}

// Round 9
// 369.829 us; speedup vs baseline: 1.5922x; 1.5922x over previous
//
#include <hip/hip_runtime.h>
#include <cstdint>

// ---------------------------------------------------------------------------
// ConvModule: LN -> GEMM(512->1024)+SiLU -> conv K=5 (1024->1024) -> GLU ->
//             BN -> GEMM(512->512).  B=16, T=1024, C=512. fp32 I/O, bf16 MFMA.
// Round 9: conv all-LDS with 128Mx64N tile -> A+B full double-buffer fits in
// 70.6 KB -> 2 blocks/CU, ONE barrier/chunk, relay staging in NAMED uint4
// regs only (R8's indexed relay arrays went to scratch: 300MB WRITE_SIZE).
// gemm_bt kept from R8 (all-LDS, 3 blocks/CU — cut non-conv 176->138us).
// Lessons: direct-global frag loads are TCP-bound ~330us (R4/R6/R7);
// indexed reg arrays spill regardless of VGPR headroom (R5/R8); 1 block/CU
// serializes barriers (R8); unpadded LDS = 8-way conflicts (R3).
// ---------------------------------------------------------------------------

#define NB    16
#define TT    1024
#define CC    512
#define C2    1024
#define TPAD  1028        // T + 4 pad rows (2 each side) per batch

typedef unsigned short u16;
typedef short bf16x8 __attribute__((ext_vector_type(8)));
typedef float f32x4  __attribute__((ext_vector_type(4)));

__device__ __forceinline__ float bf2f(u16 u) {
  union { unsigned int i; float f; } v; v.i = ((unsigned int)u) << 16; return v.f;
}
__device__ __forceinline__ u16 f2bf(float f) {
  union { float f; unsigned int i; } v; v.f = f;
  unsigned int x = v.i;
  return (u16)((x + 0x7fffu + ((x >> 16) & 1u)) >> 16);  // RNE
}

// ---------------------------------------------------------------------------
__global__ __launch_bounds__(256) void prep_k(
    const float* __restrict__ w1, u16* __restrict__ w1b,
    const float* __restrict__ w3, u16* __restrict__ w3b,
    u16* __restrict__ h1p) {
  const int b = blockIdx.x;
  if (b < 512) {
    const int i = (b * 256 + threadIdx.x) * 4;
    float4 v = *(const float4*)(w1 + i);
    u16 o[4] = { f2bf(v.x), f2bf(v.y), f2bf(v.z), f2bf(v.w) };
    *(uint2*)(w1b + i) = *(const uint2*)o;
  } else if (b < 768) {
    const int i = ((b - 512) * 256 + threadIdx.x) * 4;
    float4 v = *(const float4*)(w3 + i);
    u16 o[4] = { f2bf(v.x), f2bf(v.y), f2bf(v.z), f2bf(v.w) };
    *(uint2*)(w3b + i) = *(const uint2*)o;
  } else {
    const int idx = (b - 768) * 256 + threadIdx.x;
    const int bb  = idx >> 9;
    const int rem = idx & 511;
    const int ri  = rem >> 7;
    const int c8  = (rem & 127) * 8;
    const int row = bb * TPAD + (ri < 2 ? ri : 1024 + ri);   // 0,1,1026,1027
    uint4 z = make_uint4(0u, 0u, 0u, 0u);
    *(uint4*)(h1p + (size_t)row * C2 + c8) = z;
  }
}

// ---------------------------------------------------------------------------
// w2 fp32 (K, I, O) -> w2t bf16 (K, O, I)
__global__ void transpose_w2(const float* __restrict__ w2, u16* __restrict__ w2t) {
  __shared__ u16 t[64][65];
  const int k  = blockIdx.z;
  const int i0 = blockIdx.x * 64, o0 = blockIdx.y * 64;
  const int tx = threadIdx.x, ty = threadIdx.y;
  for (int r = ty; r < 64; r += 4)
    t[r][tx] = f2bf(w2[((size_t)(k * C2) + i0 + r) * C2 + o0 + tx]);
  __syncthreads();
  for (int r = ty; r < 64; r += 4)
    w2t[((size_t)(k * C2) + o0 + r) * C2 + i0 + tx] = t[tx][r];
}

// ---------------------------------------------------------------------------
__global__ __launch_bounds__(256) void layernorm_k(
    const float* __restrict__ x, const float* __restrict__ lng,
    const float* __restrict__ lnb, u16* __restrict__ out) {
  const int tok  = blockIdx.x * 4 + (threadIdx.x >> 6);
  const int lane = threadIdx.x & 63;
  const float* xp = x + (size_t)tok * CC + lane * 8;
  float f[8];
  *(float4*)(f)     = *(const float4*)(xp);
  *(float4*)(f + 4) = *(const float4*)(xp + 4);
  float s = 0.f, s2 = 0.f;
#pragma unroll
  for (int j = 0; j < 8; j++) { s += f[j]; s2 += f[j] * f[j]; }
#pragma unroll
  for (int m = 32; m >= 1; m >>= 1) { s += __shfl_xor(s, m, 64); s2 += __shfl_xor(s2, m, 64); }
  const float mu  = s  * (1.f / 512.f);
  const float var = s2 * (1.f / 512.f) - mu * mu;
  const float rs  = rsqrtf(var + 1e-5f);
  u16 ov[8];
#pragma unroll
  for (int j = 0; j < 8; j++) {
    const int c = lane * 8 + j;
    ov[j] = f2bf((f[j] - mu) * rs * lng[c] + lnb[c]);
  }
  *(uint4*)(out + (size_t)tok * CC + lane * 8) = *(const uint4*)ov;
}

// ---------------------------------------------------------------------------
// GEMM out[m,n] = sum_k A[m,k]*Bt[n,k] + bias[n].  128x128 tile, BK=32.
// A and B both LDS double-buffered (stride 40), named-reg relay staging,
// 1 barrier per chunk.  3 blocks/CU.  (R8 version — kept.)
template <int EPI>
__global__ __launch_bounds__(256, 3) void gemm_bt(
    const u16* __restrict__ A, const u16* __restrict__ Bt,
    const float* __restrict__ bias, void* __restrict__ outv,
    const int Kd, const int ldA) {
  __shared__ __align__(16) u16 smem[20480];   // lsA 2x5120 | lsB 2x5120
  const int tid  = threadIdx.x;
  const int m0   = blockIdx.x * 128;
  const int n0   = blockIdx.y * 128;
  const int wave = tid >> 6, lane = tid & 63;
  const int wm = (wave & 1) * 64, wn = (wave >> 1) * 64;
  const int quad = lane >> 4, l16 = lane & 15;
  const int row = tid >> 2;            // 0..63
  const int kc  = (tid & 3) * 8;       // 0/8/16/24
  const int J = Kd >> 5;               // 16

  const u16* Ap0 = A + (size_t)(m0 + row) * ldA + kc;
  const u16* Ap1 = Ap0 + (size_t)64 * ldA;
  const u16* Bp0 = Bt + (size_t)(n0 + row) * Kd + kc;
  const u16* Bp1 = Bp0 + (size_t)64 * Kd;

  f32x4 acc[4][4] = {};
  uint4 rA0 = *(const uint4*)Ap0, rA1 = *(const uint4*)Ap1;
  uint4 rB0 = *(const uint4*)Bp0, rB1 = *(const uint4*)Bp1;
  *(uint4*)(smem + row * 40 + kc)                = rA0;
  *(uint4*)(smem + (64 + row) * 40 + kc)         = rA1;
  *(uint4*)(smem + 10240 + row * 40 + kc)        = rB0;
  *(uint4*)(smem + 10240 + (64 + row) * 40 + kc) = rB1;
  rA0 = *(const uint4*)(Ap0 + 32); rA1 = *(const uint4*)(Ap1 + 32);
  rB0 = *(const uint4*)(Bp0 + 32); rB1 = *(const uint4*)(Bp1 + 32);
  __syncthreads();

#pragma unroll 1
  for (int j = 0; j < J; j++) {
    const u16* curA = smem + (j & 1) * 5120;
    const u16* curB = smem + 10240 + (j & 1) * 5120;
    if (j + 1 < J) {
      u16* nxtA = smem + ((j + 1) & 1) * 5120;
      u16* nxtB = smem + 10240 + ((j + 1) & 1) * 5120;
      *(uint4*)(nxtA + row * 40 + kc)        = rA0;
      *(uint4*)(nxtA + (64 + row) * 40 + kc) = rA1;
      *(uint4*)(nxtB + row * 40 + kc)        = rB0;
      *(uint4*)(nxtB + (64 + row) * 40 + kc) = rB1;
    }
    {
      const int k2 = (j + 2 < J) ? (j + 2) * 32 : 0;
      rA0 = *(const uint4*)(Ap0 + k2); rA1 = *(const uint4*)(Ap1 + k2);
      rB0 = *(const uint4*)(Bp0 + k2); rB1 = *(const uint4*)(Bp1 + k2);
    }
    bf16x8 af[4], bfr[4];
#pragma unroll
    for (int i = 0; i < 4; i++)
      af[i] = *(const bf16x8*)(curA + (wm + i * 16 + l16) * 40 + quad * 8);
#pragma unroll
    for (int i = 0; i < 4; i++)
      bfr[i] = *(const bf16x8*)(curB + (wn + i * 16 + l16) * 40 + quad * 8);
#pragma unroll
    for (int mi = 0; mi < 4; mi++)
#pragma unroll
      for (int ni = 0; ni < 4; ni++)
        acc[mi][ni] = __builtin_amdgcn_mfma_f32_16x16x32_bf16(
            af[mi], bfr[ni], acc[mi][ni], 0, 0, 0);
    __syncthreads();
  }

  float bv[4];
#pragma unroll
  for (int ni = 0; ni < 4; ni++) bv[ni] = bias[n0 + wn + ni * 16 + l16];

  if (EPI == 0) {
    u16* epi = smem + wave * 4608;       // 64 x 72 u16, private
#pragma unroll
    for (int mi = 0; mi < 4; mi++)
#pragma unroll
      for (int ni = 0; ni < 4; ni++)
#pragma unroll
        for (int r = 0; r < 4; r++) {
          float v = acc[mi][ni][r] + bv[ni];
          v = v / (1.f + __expf(-v));    // SiLU
          epi[(mi * 16 + quad * 4 + r) * 72 + ni * 16 + l16] = f2bf(v);
        }
    u16* h1p = (u16*)outv;
#pragma unroll
    for (int p = 0; p < 8; p++) {
      const int rrow = p * 8 + (lane >> 3);
      const int colb = (lane & 7) * 8;
      uint4 v = *(const uint4*)(epi + rrow * 72 + colb);
      const int rr = m0 + wm + rrow;
      const int bb = rr >> 10, tt = rr & 1023;
      *(uint4*)(h1p + (size_t)(bb * TPAD + tt + 2) * C2 + n0 + wn + colb) = v;
    }
  } else {
    float* fepi = (float*)(smem + wave * 4608);   // 2 x (16 x 68) f32
    float* outf = (float*)outv;
#pragma unroll
    for (int mi = 0; mi < 4; mi++) {
      float* fp = fepi + (mi & 1) * 1088;
#pragma unroll
      for (int ni = 0; ni < 4; ni++)
#pragma unroll
        for (int r = 0; r < 4; r++)
          fp[(quad * 4 + r) * 68 + ni * 16 + l16] = acc[mi][ni][r] + bv[ni];
#pragma unroll
      for (int p = 0; p < 4; p++) {
        const int rrow = p * 4 + (lane >> 4);
        const int col  = (lane & 15) * 4;
        float4 v = *(const float4*)(fp + rrow * 68 + col);
        *(float4*)(outf + (size_t)(m0 + wm + mi * 16 + rrow) * CC + n0 + wn + col) = v;
      }
    }
  }
}

// ---------------------------------------------------------------------------
// 5-tap conv: 128M x 64N tile.  A (132x32) + B (5x64x32) both LDS
// double-buffered (stride 40), named-uint4 relay staging (rA0-2, rB0-4),
// ONE barrier per chunk.  LDS 70.6 KB -> 2 blocks/CU.
__global__ __launch_bounds__(256, 2) void conv5_mfma(
    const u16* __restrict__ h1p, const u16* __restrict__ w2t,
    const float* __restrict__ b2, u16* __restrict__ out) {
  __shared__ __align__(16) u16 smem[36160];  // lsA 2x5280 | lsB 2x12800 @10560
  const int tid = threadIdx.x;
  const int mt  = blockIdx.x;                // m-tile 0..127
  const int n0  = blockIdx.y * 64;           // n-tile 0..15
  const int bb  = mt >> 3;
  const int t0  = (mt & 7) * 128;
  const size_t arow0 = (size_t)bb * TPAD + t0;
  const int wave = tid >> 6, lane = tid & 63;
  const int wm = (wave & 1) * 64, wn = (wave >> 1) * 32;
  const int quad = lane >> 4, l16 = lane & 15;
  const int row = tid >> 2;            // 0..63
  const int kc  = (tid & 3) * 8;       // 0/8/16/24

  const u16* Ap0 = h1p + (arow0 + row) * C2 + kc;
  const u16* Ap1 = Ap0 + (size_t)64 * C2;
  const u16* Ap2 = h1p + (arow0 + 128 + row) * C2 + kc;   // tid<16: rows 128..131
  const u16* Bp  = w2t + (size_t)(n0 + row) * C2 + kc;    // + tap*C2*C2 + i0

  f32x4 acc[4][2] = {};
  uint4 rA0, rA1, rA2, rB0, rB1, rB2, rB3, rB4;

#define BLD(R, T, I0) R = *(const uint4*)(Bp + (size_t)(T) * C2 * C2 + (I0));
#define BST(R, T, DST) *(uint4*)((DST) + (T) * 2560 + row * 40 + kc) = R;

  // prologue: chunk0 -> buf0
  rA0 = *(const uint4*)Ap0; rA1 = *(const uint4*)Ap1;
  if (tid < 16) rA2 = *(const uint4*)Ap2;
  BLD(rB0, 0, 0) BLD(rB1, 1, 0) BLD(rB2, 2, 0) BLD(rB3, 3, 0) BLD(rB4, 4, 0)
  *(uint4*)(smem + row * 40 + kc)        = rA0;
  *(uint4*)(smem + (64 + row) * 40 + kc) = rA1;
  if (tid < 16) *(uint4*)(smem + (128 + row) * 40 + kc) = rA2;
  {
    u16* b0 = smem + 10560;
    BST(rB0, 0, b0) BST(rB1, 1, b0) BST(rB2, 2, b0) BST(rB3, 3, b0) BST(rB4, 4, b0)
  }
  // chunk1 -> regs
  rA0 = *(const uint4*)(Ap0 + 32); rA1 = *(const uint4*)(Ap1 + 32);
  if (tid < 16) rA2 = *(const uint4*)(Ap2 + 32);
  BLD(rB0, 0, 32) BLD(rB1, 1, 32) BLD(rB2, 2, 32) BLD(rB3, 3, 32) BLD(rB4, 4, 32)
  __syncthreads();

#pragma unroll 1
  for (int j = 0; j < 32; j++) {
    const u16* curA = smem + (j & 1) * 5280;
    const u16* curB = smem + 10560 + (j & 1) * 12800;
    // 1) write chunk j+1 from relay regs (loads are 1 chunk old)
    if (j + 1 < 32) {
      u16* nxtA = smem + ((j + 1) & 1) * 5280;
      u16* nxtB = smem + 10560 + ((j + 1) & 1) * 12800;
      *(uint4*)(nxtA + row * 40 + kc)        = rA0;
      *(uint4*)(nxtA + (64 + row) * 40 + kc) = rA1;
      if (tid < 16) *(uint4*)(nxtA + (128 + row) * 40 + kc) = rA2;
      BST(rB0, 0, nxtB) BST(rB1, 1, nxtB) BST(rB2, 2, nxtB)
      BST(rB3, 3, nxtB) BST(rB4, 4, nxtB)
    }
    // 2) relay loads for chunk j+2 (full chunk of latency cover)
    {
      const int i2 = (j + 2 < 32) ? (j + 2) * 32 : 0;
      rA0 = *(const uint4*)(Ap0 + i2);
      rA1 = *(const uint4*)(Ap1 + i2);
      if (tid < 16) rA2 = *(const uint4*)(Ap2 + i2);
      BLD(rB0, 0, i2) BLD(rB1, 1, i2) BLD(rB2, 2, i2)
      BLD(rB3, 3, i2) BLD(rB4, 4, i2)
    }
    // 3) compute chunk j: 5 taps x (4 mi x 2 ni) MFMA
#pragma unroll
    for (int k = 0; k < 5; k++) {
      bf16x8 af[4], bfr[2];
#pragma unroll
      for (int i = 0; i < 4; i++)
        af[i] = *(const bf16x8*)(curA + (wm + i * 16 + l16 + k) * 40 + quad * 8);
#pragma unroll
      for (int i = 0; i < 2; i++)
        bfr[i] = *(const bf16x8*)(curB + k * 2560 + (wn + i * 16 + l16) * 40 + quad * 8);
#pragma unroll
      for (int mi = 0; mi < 4; mi++)
#pragma unroll
        for (int ni = 0; ni < 2; ni++)
          acc[mi][ni] = __builtin_amdgcn_mfma_f32_16x16x32_bf16(
              af[mi], bfr[ni], acc[mi][ni], 0, 0, 0);
    }
    __syncthreads();
  }
#undef BLD
#undef BST

  float bv[2];
#pragma unroll
  for (int ni = 0; ni < 2; ni++) bv[ni] = b2[n0 + wn + ni * 16 + l16];

  u16* epi = smem + wave * 4608;         // 64 x 36 u16, private per wave
#pragma unroll
  for (int mi = 0; mi < 4; mi++)
#pragma unroll
    for (int ni = 0; ni < 2; ni++)
#pragma unroll
      for (int r = 0; r < 4; r++)
        epi[(mi * 16 + quad * 4 + r) * 36 + ni * 16 + l16] = f2bf(acc[mi][ni][r] + bv[ni]);

  const size_t orow0 = (size_t)bb * TT + t0;
#pragma unroll
  for (int p = 0; p < 4; p++) {
    const int rrow = p * 16 + (lane >> 2);
    const int colb = (lane & 3) * 8;
    uint4 v = *(const uint4*)(epi + rrow * 36 + colb);
    *(uint4*)(out + (orow0 + wm + rrow) * C2 + n0 + wn + colb) = v;
  }
}

// ---------------------------------------------------------------------------
__global__ __launch_bounds__(256) void glu_bn_k(
    const u16* __restrict__ hc, const float* __restrict__ bg,
    const float* __restrict__ bb_, const float* __restrict__ bm,
    const float* __restrict__ bv, u16* __restrict__ out) {
  const int idx = blockIdx.x * 256 + threadIdx.x;
  const int r  = idx >> 6;
  const int c8 = (idx & 63) * 8;
  const u16* pa = hc + (size_t)r * C2 + c8;
  uint4 ra = *(const uint4*)pa;
  uint4 rg = *(const uint4*)(pa + CC);
  u16 av[8], gv[8], ov[8];
  *(uint4*)av = ra; *(uint4*)gv = rg;
#pragma unroll
  for (int j = 0; j < 8; j++) {
    const int c = c8 + j;
    const float a = bf2f(av[j]);
    const float g = bf2f(gv[j]);
    const float h = a / (1.f + __expf(-g));
    const float sc = bg[c] * rsqrtf(bv[c] + 1e-5f);
    ov[j] = f2bf((h - bm[c]) * sc + bb_[c]);
  }
  *(uint4*)(out + (size_t)r * CC + c8) = *(const uint4*)ov;
}

// ---------------------------------------------------------------------------
extern "C" void kernel_launch(void* const* d_in, const int* in_sizes, int n_in,
                              void* d_out, int out_size, void* d_ws, size_t ws_size,
                              hipStream_t stream) {
  const float* x   = (const float*)d_in[0];
  const float* lng = (const float*)d_in[1];
  const float* lnb = (const float*)d_in[2];
  const float* w1  = (const float*)d_in[3];
  const float* b1  = (const float*)d_in[4];
  const float* w2  = (const float*)d_in[5];
  const float* b2  = (const float*)d_in[6];
  const float* bng = (const float*)d_in[7];
  const float* bnb = (const float*)d_in[8];
  const float* bnm = (const float*)d_in[9];
  const float* bnv = (const float*)d_in[10];
  const float* w3  = (const float*)d_in[11];
  const float* b3  = (const float*)d_in[12];

  u16* ws  = (u16*)d_ws;
  u16* hln = ws;                               // 16384*512
  u16* h2  = hln;                              // alias (hln dead after GEMM1)
  u16* h1p = ws + 8388608;                     // 16*1028*1024
  u16* w2t = h1p + 16842752;                   // 5*1024*1024
  u16* hcv = w2t + 5242880;                    // 16384*1024
  u16* w1b = hcv + 16777216;                   // 1024*512
  u16* w3b = w1b + 524288;                     // 512*512

  prep_k      <<<800, 256, 0, stream>>>(w1, w1b, w3, w3b, h1p);
  transpose_w2<<<dim3(16, 16, 5), dim3(64, 4), 0, stream>>>(w2, w2t);
  layernorm_k <<<4096, 256, 0, stream>>>(x, lng, lnb, hln);
  gemm_bt<0>  <<<dim3(128, 8), 256, 0, stream>>>(hln, w1b, b1, h1p, 512, 512);
  conv5_mfma  <<<dim3(128, 16), 256, 0, stream>>>(h1p, w2t, b2, hcv);
  glu_bn_k    <<<4096, 256, 0, stream>>>(hcv, bng, bnb, bnm, bnv, h2);
  gemm_bt<1>  <<<dim3(128, 4), 256, 0, stream>>>(h2, w3b, b3, d_out, 512, 512);
}

// Round 10
// 360.900 us; speedup vs baseline: 1.6316x; 1.0247x over previous
//
#include <hip/hip_runtime.h>
#include <cstdint>

// ---------------------------------------------------------------------------
// ConvModule: LN -> GEMM(512->1024)+SiLU -> conv K=5 (1024->1024) -> GLU ->
//             BN -> GEMM(512->512).  B=16, T=1024, C=512. fp32 I/O, bf16 MFMA.
// Round 10: conv 128x128 block (64x64 wave tiles: LDS reads/output -33%,
// MFMA/barrier x2) + B in FRAGMENT-MAJOR single-buffered LDS (lane-linear
// b128 reads = conflict-free; staging = perfect permutation), A row-major
// stride-40 double-buffered (taps need row shifts). 2 barriers/chunk,
// 62 KB LDS -> 2 blocks/CU.  B relay = 10 NAMED uint4 via macros.
// Lessons: indexed reg arrays spill (R5/R8); named scalars don't (R9);
// direct-global frags TCP-bound (R4/R6/R7); stride-40 row-major frag reads
// cost ~6 extra cyc/read in conflicts (R9) -> frag-major where possible.
// ---------------------------------------------------------------------------

#define NB    16
#define TT    1024
#define CC    512
#define C2    1024
#define TPAD  1028        // T + 4 pad rows (2 each side) per batch

typedef unsigned short u16;
typedef short bf16x8 __attribute__((ext_vector_type(8)));
typedef float f32x4  __attribute__((ext_vector_type(4)));

__device__ __forceinline__ float bf2f(u16 u) {
  union { unsigned int i; float f; } v; v.i = ((unsigned int)u) << 16; return v.f;
}
__device__ __forceinline__ u16 f2bf(float f) {
  union { float f; unsigned int i; } v; v.f = f;
  unsigned int x = v.i;
  return (u16)((x + 0x7fffu + ((x >> 16) & 1u)) >> 16);  // RNE
}

// ---------------------------------------------------------------------------
__global__ __launch_bounds__(256) void prep_k(
    const float* __restrict__ w1, u16* __restrict__ w1b,
    const float* __restrict__ w3, u16* __restrict__ w3b,
    u16* __restrict__ h1p) {
  const int b = blockIdx.x;
  if (b < 512) {
    const int i = (b * 256 + threadIdx.x) * 4;
    float4 v = *(const float4*)(w1 + i);
    u16 o[4] = { f2bf(v.x), f2bf(v.y), f2bf(v.z), f2bf(v.w) };
    *(uint2*)(w1b + i) = *(const uint2*)o;
  } else if (b < 768) {
    const int i = ((b - 512) * 256 + threadIdx.x) * 4;
    float4 v = *(const float4*)(w3 + i);
    u16 o[4] = { f2bf(v.x), f2bf(v.y), f2bf(v.z), f2bf(v.w) };
    *(uint2*)(w3b + i) = *(const uint2*)o;
  } else {
    const int idx = (b - 768) * 256 + threadIdx.x;
    const int bb  = idx >> 9;
    const int rem = idx & 511;
    const int ri  = rem >> 7;
    const int c8  = (rem & 127) * 8;
    const int row = bb * TPAD + (ri < 2 ? ri : 1024 + ri);   // 0,1,1026,1027
    uint4 z = make_uint4(0u, 0u, 0u, 0u);
    *(uint4*)(h1p + (size_t)row * C2 + c8) = z;
  }
}

// ---------------------------------------------------------------------------
// w2 fp32 (K, I, O) -> w2t bf16 (K, O, I)
__global__ void transpose_w2(const float* __restrict__ w2, u16* __restrict__ w2t) {
  __shared__ u16 t[64][65];
  const int k  = blockIdx.z;
  const int i0 = blockIdx.x * 64, o0 = blockIdx.y * 64;
  const int tx = threadIdx.x, ty = threadIdx.y;
  for (int r = ty; r < 64; r += 4)
    t[r][tx] = f2bf(w2[((size_t)(k * C2) + i0 + r) * C2 + o0 + tx]);
  __syncthreads();
  for (int r = ty; r < 64; r += 4)
    w2t[((size_t)(k * C2) + o0 + r) * C2 + i0 + tx] = t[tx][r];
}

// ---------------------------------------------------------------------------
__global__ __launch_bounds__(256) void layernorm_k(
    const float* __restrict__ x, const float* __restrict__ lng,
    const float* __restrict__ lnb, u16* __restrict__ out) {
  const int tok  = blockIdx.x * 4 + (threadIdx.x >> 6);
  const int lane = threadIdx.x & 63;
  const float* xp = x + (size_t)tok * CC + lane * 8;
  float f[8];
  *(float4*)(f)     = *(const float4*)(xp);
  *(float4*)(f + 4) = *(const float4*)(xp + 4);
  float s = 0.f, s2 = 0.f;
#pragma unroll
  for (int j = 0; j < 8; j++) { s += f[j]; s2 += f[j] * f[j]; }
#pragma unroll
  for (int m = 32; m >= 1; m >>= 1) { s += __shfl_xor(s, m, 64); s2 += __shfl_xor(s2, m, 64); }
  const float mu  = s  * (1.f / 512.f);
  const float var = s2 * (1.f / 512.f) - mu * mu;
  const float rs  = rsqrtf(var + 1e-5f);
  u16 ov[8];
#pragma unroll
  for (int j = 0; j < 8; j++) {
    const int c = lane * 8 + j;
    ov[j] = f2bf((f[j] - mu) * rs * lng[c] + lnb[c]);
  }
  *(uint4*)(out + (size_t)tok * CC + lane * 8) = *(const uint4*)ov;
}

// ---------------------------------------------------------------------------
// GEMM out[m,n] = sum_k A[m,k]*Bt[n,k] + bias[n].  128x128 tile, BK=32.
// (R8/R9 version — proven, kept.)
template <int EPI>
__global__ __launch_bounds__(256, 3) void gemm_bt(
    const u16* __restrict__ A, const u16* __restrict__ Bt,
    const float* __restrict__ bias, void* __restrict__ outv,
    const int Kd, const int ldA) {
  __shared__ __align__(16) u16 smem[20480];   // lsA 2x5120 | lsB 2x5120
  const int tid  = threadIdx.x;
  const int m0   = blockIdx.x * 128;
  const int n0   = blockIdx.y * 128;
  const int wave = tid >> 6, lane = tid & 63;
  const int wm = (wave & 1) * 64, wn = (wave >> 1) * 64;
  const int quad = lane >> 4, l16 = lane & 15;
  const int row = tid >> 2;            // 0..63
  const int kc  = (tid & 3) * 8;       // 0/8/16/24
  const int J = Kd >> 5;               // 16

  const u16* Ap0 = A + (size_t)(m0 + row) * ldA + kc;
  const u16* Ap1 = Ap0 + (size_t)64 * ldA;
  const u16* Bp0 = Bt + (size_t)(n0 + row) * Kd + kc;
  const u16* Bp1 = Bp0 + (size_t)64 * Kd;

  f32x4 acc[4][4] = {};
  uint4 rA0 = *(const uint4*)Ap0, rA1 = *(const uint4*)Ap1;
  uint4 rB0 = *(const uint4*)Bp0, rB1 = *(const uint4*)Bp1;
  *(uint4*)(smem + row * 40 + kc)                = rA0;
  *(uint4*)(smem + (64 + row) * 40 + kc)         = rA1;
  *(uint4*)(smem + 10240 + row * 40 + kc)        = rB0;
  *(uint4*)(smem + 10240 + (64 + row) * 40 + kc) = rB1;
  rA0 = *(const uint4*)(Ap0 + 32); rA1 = *(const uint4*)(Ap1 + 32);
  rB0 = *(const uint4*)(Bp0 + 32); rB1 = *(const uint4*)(Bp1 + 32);
  __syncthreads();

#pragma unroll 1
  for (int j = 0; j < J; j++) {
    const u16* curA = smem + (j & 1) * 5120;
    const u16* curB = smem + 10240 + (j & 1) * 5120;
    if (j + 1 < J) {
      u16* nxtA = smem + ((j + 1) & 1) * 5120;
      u16* nxtB = smem + 10240 + ((j + 1) & 1) * 5120;
      *(uint4*)(nxtA + row * 40 + kc)        = rA0;
      *(uint4*)(nxtA + (64 + row) * 40 + kc) = rA1;
      *(uint4*)(nxtB + row * 40 + kc)        = rB0;
      *(uint4*)(nxtB + (64 + row) * 40 + kc) = rB1;
    }
    {
      const int k2 = (j + 2 < J) ? (j + 2) * 32 : 0;
      rA0 = *(const uint4*)(Ap0 + k2); rA1 = *(const uint4*)(Ap1 + k2);
      rB0 = *(const uint4*)(Bp0 + k2); rB1 = *(const uint4*)(Bp1 + k2);
    }
    bf16x8 af[4], bfr[4];
#pragma unroll
    for (int i = 0; i < 4; i++)
      af[i] = *(const bf16x8*)(curA + (wm + i * 16 + l16) * 40 + quad * 8);
#pragma unroll
    for (int i = 0; i < 4; i++)
      bfr[i] = *(const bf16x8*)(curB + (wn + i * 16 + l16) * 40 + quad * 8);
#pragma unroll
    for (int mi = 0; mi < 4; mi++)
#pragma unroll
      for (int ni = 0; ni < 4; ni++)
        acc[mi][ni] = __builtin_amdgcn_mfma_f32_16x16x32_bf16(
            af[mi], bfr[ni], acc[mi][ni], 0, 0, 0);
    __syncthreads();
  }

  float bv[4];
#pragma unroll
  for (int ni = 0; ni < 4; ni++) bv[ni] = bias[n0 + wn + ni * 16 + l16];

  if (EPI == 0) {
    u16* epi = smem + wave * 4608;       // 64 x 72 u16, private
#pragma unroll
    for (int mi = 0; mi < 4; mi++)
#pragma unroll
      for (int ni = 0; ni < 4; ni++)
#pragma unroll
        for (int r = 0; r < 4; r++) {
          float v = acc[mi][ni][r] + bv[ni];
          v = v / (1.f + __expf(-v));    // SiLU
          epi[(mi * 16 + quad * 4 + r) * 72 + ni * 16 + l16] = f2bf(v);
        }
    u16* h1p = (u16*)outv;
#pragma unroll
    for (int p = 0; p < 8; p++) {
      const int rrow = p * 8 + (lane >> 3);
      const int colb = (lane & 7) * 8;
      uint4 v = *(const uint4*)(epi + rrow * 72 + colb);
      const int rr = m0 + wm + rrow;
      const int bb = rr >> 10, tt = rr & 1023;
      *(uint4*)(h1p + (size_t)(bb * TPAD + tt + 2) * C2 + n0 + wn + colb) = v;
    }
  } else {
    float* fepi = (float*)(smem + wave * 4608);   // 2 x (16 x 68) f32
    float* outf = (float*)outv;
#pragma unroll
    for (int mi = 0; mi < 4; mi++) {
      float* fp = fepi + (mi & 1) * 1088;
#pragma unroll
      for (int ni = 0; ni < 4; ni++)
#pragma unroll
        for (int r = 0; r < 4; r++)
          fp[(quad * 4 + r) * 68 + ni * 16 + l16] = acc[mi][ni][r] + bv[ni];
#pragma unroll
      for (int p = 0; p < 4; p++) {
        const int rrow = p * 4 + (lane >> 4);
        const int col  = (lane & 15) * 4;
        float4 v = *(const float4*)(fp + rrow * 68 + col);
        *(float4*)(outf + (size_t)(m0 + wm + mi * 16 + rrow) * CC + n0 + wn + col) = v;
      }
    }
  }
}

// ---------------------------------------------------------------------------
// 5-tap conv: 128M x 128N block, 64x64 wave tiles.
// A: row-major stride-40, double-buffered (rows 0..131, taps read +k shift).
// B: FRAG-MAJOR single-buffered: tap t frag-tile g (16n x 32k = 1KB) at
//    lsB + t*4096 + g*512 (u16); element (n,k) in 16B block
//    lane' = (k>>3)*16 + (n&15).  Reads = lane-linear (conflict-free).
// 2 barriers/chunk; relay: A named rA0-2 (2-chunk dist), B named rB0-9
// (1-chunk dist, >= 388 cyc MFMA cover).
__global__ __launch_bounds__(256, 2) void conv5_mfma(
    const u16* __restrict__ h1p, const u16* __restrict__ w2t,
    const float* __restrict__ b2, u16* __restrict__ out) {
  __shared__ __align__(16) u16 smem[31040];  // lsA 2x5280 | lsB 20480 @10560
  const int tid = threadIdx.x;
  const int mt  = blockIdx.x;                // m-tile 0..127
  const int n0  = blockIdx.y * 128;          // n-tile 0..7
  const int bb  = mt >> 3;
  const int t0  = (mt & 7) * 128;
  const size_t arow0 = (size_t)bb * TPAD + t0;
  const int wave = tid >> 6, lane = tid & 63;
  const int wm = (wave & 1) * 64, wn = (wave >> 1) * 64;
  const int quad = lane >> 4, l16 = lane & 15;
  const int row = tid >> 2;            // 0..63
  const int kc  = (tid & 3) * 8;       // 0/8/16/24
  u16* lsB = smem + 10560;

  const u16* Ap0 = h1p + (arow0 + row) * C2 + kc;
  const u16* Ap1 = Ap0 + (size_t)64 * C2;
  const u16* Ap2 = h1p + (arow0 + 128 + row) * C2 + kc;   // tid<16: rows 128..131

  f32x4 acc[4][4] = {};
  uint4 rA0, rA1, rA2, rB0, rB1, rB2, rB3, rB4, rB5, rB6, rB7, rB8, rB9;

  // B relay: slot Q covers tap Q>>1, u = (Q&1)*256+tid -> n = n0+(u>>2),
  // k-range (u&3)*8..+8 at chunk offset I0.
#define BGLD(R, Q, I0) { const int u = ((Q) & 1) * 256 + tid;                  \
    R = *(const uint4*)(w2t + (size_t)(((Q) >> 1) * C2 + n0 + (u >> 2)) * C2   \
                        + (I0) + (u & 3) * 8); }
#define BSTF(R, Q) { const int u = ((Q) & 1) * 256 + tid; const int nn = u >> 2; \
    *(uint4*)(lsB + ((Q) >> 1) * 4096 + (nn >> 4) * 512                        \
              + ((u & 3) * 16 + (nn & 15)) * 8) = R; }
#define BGLD_ALL(I0) BGLD(rB0,0,I0) BGLD(rB1,1,I0) BGLD(rB2,2,I0) \
    BGLD(rB3,3,I0) BGLD(rB4,4,I0) BGLD(rB5,5,I0) BGLD(rB6,6,I0)   \
    BGLD(rB7,7,I0) BGLD(rB8,8,I0) BGLD(rB9,9,I0)
#define BSTF_ALL() BSTF(rB0,0) BSTF(rB1,1) BSTF(rB2,2) BSTF(rB3,3) \
    BSTF(rB4,4) BSTF(rB5,5) BSTF(rB6,6) BSTF(rB7,7) BSTF(rB8,8) BSTF(rB9,9)

  // prologue: A(0) -> bufA0; B(0) -> regs; A(1) -> regs
  rA0 = *(const uint4*)Ap0; rA1 = *(const uint4*)Ap1;
  if (tid < 16) rA2 = *(const uint4*)Ap2;
  *(uint4*)(smem + row * 40 + kc)        = rA0;
  *(uint4*)(smem + (64 + row) * 40 + kc) = rA1;
  if (tid < 16) *(uint4*)(smem + (128 + row) * 40 + kc) = rA2;
  BGLD_ALL(0)
  rA0 = *(const uint4*)(Ap0 + 32); rA1 = *(const uint4*)(Ap1 + 32);
  if (tid < 16) rA2 = *(const uint4*)(Ap2 + 32);

#pragma unroll 1
  for (int j = 0; j < 32; j++) {
    __syncthreads();                       // lsB reads of j-1 complete
    BSTF_ALL()                             // lsB = B(j)
    {                                      // bufA[(j+1)&1] = A(j+1)
      u16* nxtA = smem + ((j + 1) & 1) * 5280;
      *(uint4*)(nxtA + row * 40 + kc)        = rA0;
      *(uint4*)(nxtA + (64 + row) * 40 + kc) = rA1;
      if (tid < 16) *(uint4*)(nxtA + (128 + row) * 40 + kc) = rA2;
    }
    __syncthreads();                       // lsB/bufA visible
    {                                      // relay loads: B(j+1), A(j+2)
      const int ib = (j + 1 < 32) ? (j + 1) * 32 : 0;
      BGLD_ALL(ib)
      const int ia = (j + 2 < 32) ? (j + 2) * 32 : 0;
      rA0 = *(const uint4*)(Ap0 + ia);
      rA1 = *(const uint4*)(Ap1 + ia);
      if (tid < 16) rA2 = *(const uint4*)(Ap2 + ia);
    }
    const u16* curA = smem + (j & 1) * 5280;
#pragma unroll
    for (int k = 0; k < 5; k++) {
      bf16x8 af[4], bfr[4];
#pragma unroll
      for (int i = 0; i < 4; i++)
        af[i] = *(const bf16x8*)(curA + (wm + i * 16 + l16 + k) * 40 + quad * 8);
#pragma unroll
      for (int i = 0; i < 4; i++)
        bfr[i] = *(const bf16x8*)(lsB + k * 4096 + ((wn >> 4) + i) * 512 + lane * 8);
#pragma unroll
      for (int mi = 0; mi < 4; mi++)
#pragma unroll
        for (int ni = 0; ni < 4; ni++)
          acc[mi][ni] = __builtin_amdgcn_mfma_f32_16x16x32_bf16(
              af[mi], bfr[ni], acc[mi][ni], 0, 0, 0);
    }
  }
#undef BGLD
#undef BSTF
#undef BGLD_ALL
#undef BSTF_ALL
  __syncthreads();

  float bv[4];
#pragma unroll
  for (int ni = 0; ni < 4; ni++) bv[ni] = b2[n0 + wn + ni * 16 + l16];

  u16* epi = smem + wave * 4608;         // 64 x 72 u16, private per wave
#pragma unroll
  for (int mi = 0; mi < 4; mi++)
#pragma unroll
    for (int ni = 0; ni < 4; ni++)
#pragma unroll
      for (int r = 0; r < 4; r++)
        epi[(mi * 16 + quad * 4 + r) * 72 + ni * 16 + l16] = f2bf(acc[mi][ni][r] + bv[ni]);

  const size_t orow0 = (size_t)bb * TT + t0;
#pragma unroll
  for (int p = 0; p < 8; p++) {
    const int rrow = p * 8 + (lane >> 3);
    const int colb = (lane & 7) * 8;
    uint4 v = *(const uint4*)(epi + rrow * 72 + colb);
    *(uint4*)(out + (orow0 + wm + rrow) * C2 + n0 + wn + colb) = v;
  }
}

// ---------------------------------------------------------------------------
__global__ __launch_bounds__(256) void glu_bn_k(
    const u16* __restrict__ hc, const float* __restrict__ bg,
    const float* __restrict__ bb_, const float* __restrict__ bm,
    const float* __restrict__ bv, u16* __restrict__ out) {
  const int idx = blockIdx.x * 256 + threadIdx.x;
  const int r  = idx >> 6;
  const int c8 = (idx & 63) * 8;
  const u16* pa = hc + (size_t)r * C2 + c8;
  uint4 ra = *(const uint4*)pa;
  uint4 rg = *(const uint4*)(pa + CC);
  u16 av[8], gv[8], ov[8];
  *(uint4*)av = ra; *(uint4*)gv = rg;
#pragma unroll
  for (int j = 0; j < 8; j++) {
    const int c = c8 + j;
    const float a = bf2f(av[j]);
    const float g = bf2f(gv[j]);
    const float h = a / (1.f + __expf(-g));
    const float sc = bg[c] * rsqrtf(bv[c] + 1e-5f);
    ov[j] = f2bf((h - bm[c]) * sc + bb_[c]);
  }
  *(uint4*)(out + (size_t)r * CC + c8) = *(const uint4*)ov;
}

// ---------------------------------------------------------------------------
extern "C" void kernel_launch(void* const* d_in, const int* in_sizes, int n_in,
                              void* d_out, int out_size, void* d_ws, size_t ws_size,
                              hipStream_t stream) {
  const float* x   = (const float*)d_in[0];
  const float* lng = (const float*)d_in[1];
  const float* lnb = (const float*)d_in[2];
  const float* w1  = (const float*)d_in[3];
  const float* b1  = (const float*)d_in[4];
  const float* w2  = (const float*)d_in[5];
  const float* b2  = (const float*)d_in[6];
  const float* bng = (const float*)d_in[7];
  const float* bnb = (const float*)d_in[8];
  const float* bnm = (const float*)d_in[9];
  const float* bnv = (const float*)d_in[10];
  const float* w3  = (const float*)d_in[11];
  const float* b3  = (const float*)d_in[12];

  u16* ws  = (u16*)d_ws;
  u16* hln = ws;                               // 16384*512
  u16* h2  = hln;                              // alias (hln dead after GEMM1)
  u16* h1p = ws + 8388608;                     // 16*1028*1024
  u16* w2t = h1p + 16842752;                   // 5*1024*1024
  u16* hcv = w2t + 5242880;                    // 16384*1024
  u16* w1b = hcv + 16777216;                   // 1024*512
  u16* w3b = w1b + 524288;                     // 512*512

  prep_k      <<<800, 256, 0, stream>>>(w1, w1b, w3, w3b, h1p);
  transpose_w2<<<dim3(16, 16, 5), dim3(64, 4), 0, stream>>>(w2, w2t);
  layernorm_k <<<4096, 256, 0, stream>>>(x, lng, lnb, hln);
  gemm_bt<0>  <<<dim3(128, 8), 256, 0, stream>>>(hln, w1b, b1, h1p, 512, 512);
  conv5_mfma  <<<dim3(128, 8), 256, 0, stream>>>(h1p, w2t, b2, hcv);
  glu_bn_k    <<<4096, 256, 0, stream>>>(hcv, bng, bnb, bnm, bnv, h2);
  gemm_bt<1>  <<<dim3(128, 4), 256, 0, stream>>>(h2, w3b, b3, d_out, 512, 512);
}